// Round 5
// baseline (56.762 us; speedup 1.0000x reference)
//
#include <hip/hip_runtime.h>

#define NB 8192
#define ND 128
#define MARGINF 0.3f
#define CAP_TILES 4        // phase-1 scans 4*64 = 256 columns
#define NCHUNK 32          // phase-2: 32 chunks x 256 columns
#define P2_GRID 2048

// d_ws layout (bytes):
//   [0]      int   count
//   [1024]   int   list[8192]
//   [33792]  float dap[8192]
//   [66560]  uint  idxmin[8192]   (init'd by scan for k < count)
//   [99328]  float row_loss[8192]

__device__ __forceinline__ float dot4(float4 x, float4 y) {
    return x.x * y.x + x.y * y.y + x.z * y.z + x.w * y.w;
}

// Butterfly sum within each 32-lane half (offsets 1..16 keep bit5 fixed).
__device__ __forceinline__ float half_reduce(float v) {
    v += __shfl_xor(v, 1, 64);
    v += __shfl_xor(v, 2, 64);
    v += __shfl_xor(v, 4, 64);
    v += __shfl_xor(v, 8, 64);
    v += __shfl_xor(v, 16, 64);
    return v;
}

// Returns first (lowest) column in [0,64) given lane ownership col(L)=2*(L&31)+(L>>5).
__device__ __forceinline__ int first_col_from_mask(unsigned long long mask) {
    const unsigned int lo = (unsigned int)mask;          // even local cols 2*L
    const unsigned int hi = (unsigned int)(mask >> 32);  // odd local cols 2*(L-32)+1
    const int ce = lo ? 2 * (__ffs(lo) - 1)     : 0x7fffffff;
    const int co = hi ? 2 * (__ffs(hi) - 1) + 1 : 0x7fffffff;
    return ce < co ? ce : co;
}

__global__ void init_count(int* __restrict__ count) {
    if (threadIdx.x == 0) *count = 0;
}

__global__ __launch_bounds__(256) void triplet_scan(const float* __restrict__ a,
                                                    const float* __restrict__ p,
                                                    const float* __restrict__ n,
                                                    int* __restrict__ count,
                                                    int* __restrict__ list,
                                                    float* __restrict__ dap,
                                                    unsigned int* __restrict__ idxmin,
                                                    float* __restrict__ row_loss) {
    const int wave = threadIdx.x >> 6;
    const int lane = threadIdx.x & 63;
    const int row  = blockIdx.x * 4 + wave;
    const int q    = lane & 31;   // quarter-row position (float4 index)
    const int h    = lane >> 5;   // half: 0 -> even column, 1 -> odd column

    const float4 a4 = *(const float4*)(a + (size_t)row * ND + q * 4);
    const float4 p4 = *(const float4*)(p + (size_t)row * ND + q * 4);
    const float dist_ap = half_reduce(dot4(a4, p4));
    const float thresh  = dist_ap + MARGINF;

    for (int t = 0; t < CAP_TILES; ++t) {
        float myval = 0.f;
        #pragma unroll
        for (int k = 0; k < 32; ++k) {
            const int col = t * 64 + 2 * k + h;
            // Coalesced: wave covers 1024 contiguous bytes (2 rows of n).
            const float4 nv = *(const float4*)(n + (size_t)col * ND + q * 4);
            const float v = half_reduce(dot4(a4, nv));
            if (q == k) myval = v;   // lane L retains col 2*(L&31)+(L>>5)
        }
        const unsigned long long mask = __ballot(myval < thresh);
        if (mask) {  // wave-uniform
            const int c   = first_col_from_mask(mask);
            const int src = (c & 1) ? 32 + (c >> 1) : (c >> 1);
            const float dist_an = __shfl(myval, src, 64);
            if (lane == 0) {
                const float l = dist_an - dist_ap + MARGINF;
                row_loss[row] = l > 0.f ? l : 0.f;
            }
            return;
        }
    }
    if (lane == 0) {
        const int k = atomicAdd(count, 1);
        list[k]   = row;
        dap[k]    = dist_ap;
        idxmin[k] = 0xFFFFFFFFu;
    }
}

// Phase 2: pair = (unresolved row w, 256-col chunk); wave handles 64 cols.
__global__ __launch_bounds__(256) void triplet_cols(const float* __restrict__ a,
                                                    const float* __restrict__ n,
                                                    const int* __restrict__ count,
                                                    const int* __restrict__ list,
                                                    const float* __restrict__ dap,
                                                    unsigned int* __restrict__ idxmin) {
    const int wave = threadIdx.x >> 6;
    const int lane = threadIdx.x & 63;
    const int q    = lane & 31;
    const int h    = lane >> 5;
    const int cnt  = *count;
    const int npairs = cnt * NCHUNK;

    for (int pair = blockIdx.x; pair < npairs; pair += gridDim.x) {
        const int w     = pair >> 5;          // / NCHUNK
        const int chunk = pair & (NCHUNK - 1);
        const int row   = list[w];
        const float4 a4 = *(const float4*)(a + (size_t)row * ND + q * 4);
        const float thresh = dap[w] + MARGINF;
        const int base = chunk * 256 + wave * 64;

        float myval = 0.f;
        #pragma unroll
        for (int k = 0; k < 32; ++k) {
            const int col = base + 2 * k + h;
            const float4 nv = *(const float4*)(n + (size_t)col * ND + q * 4);
            const float v = half_reduce(dot4(a4, nv));  // same order as scan
            if (q == k) myval = v;
        }
        const unsigned long long mask = __ballot(myval < thresh);
        if (mask) {
            const int c = first_col_from_mask(mask);
            if (lane == 0) atomicMin(&idxmin[w], (unsigned int)(base + c));
        }
    }
}

// Single block: fix up unresolved rows (recompute an[row,j]) then tree-reduce all 8192.
__global__ __launch_bounds__(256) void fixup_reduce(const float* __restrict__ a,
                                                    const float* __restrict__ n,
                                                    const int* __restrict__ count,
                                                    const int* __restrict__ list,
                                                    const float* __restrict__ dap,
                                                    const unsigned int* __restrict__ idxmin,
                                                    float* __restrict__ row_loss,
                                                    float* __restrict__ out) {
    __shared__ float s[256];
    const int tid  = threadIdx.x;
    const int lane = tid & 63;
    const int wv   = tid >> 6;           // 4 waves
    const int cnt  = *count;

    for (int w = wv; w < cnt; w += 4) {
        const int row = list[w];
        const unsigned int u = idxmin[w];
        const int j = (u == 0xFFFFFFFFu) ? row : (int)u;
        const float a0 = a[(size_t)row * ND + lane];
        const float a1 = a[(size_t)row * ND + lane + 64];
        float part = a0 * n[(size_t)j * ND + lane] + a1 * n[(size_t)j * ND + lane + 64];
        #pragma unroll
        for (int off = 32; off; off >>= 1) part += __shfl_xor(part, off, 64);
        if (lane == 0) {
            const float l = part - dap[w] + MARGINF;
            row_loss[row] = l > 0.f ? l : 0.f;
        }
    }
    __syncthreads();   // row_loss writes visible block-wide

    const float4* rl4 = (const float4*)row_loss;
    float sum = 0.f;
    #pragma unroll
    for (int i = 0; i < NB / 4 / 256; ++i) {   // 8 iterations, fixed order
        const float4 v = rl4[i * 256 + tid];
        sum += (v.x + v.y) + (v.z + v.w);
    }
    s[tid] = sum;
    __syncthreads();
    #pragma unroll
    for (int off = 128; off; off >>= 1) {
        if (tid < off) s[tid] += s[tid + off];
        __syncthreads();
    }
    if (tid == 0) out[0] = s[0] / (float)NB;
}

extern "C" void kernel_launch(void* const* d_in, const int* in_sizes, int n_in,
                              void* d_out, int out_size, void* d_ws, size_t ws_size,
                              hipStream_t stream) {
    const float* a = (const float*)d_in[0];
    const float* p = (const float*)d_in[1];
    const float* n = (const float*)d_in[2];
    char* ws = (char*)d_ws;
    int*          count    = (int*)ws;
    int*          list     = (int*)(ws + 1024);
    float*        dap      = (float*)(ws + 33792);
    unsigned int* idxmin   = (unsigned int*)(ws + 66560);
    float*        row_loss = (float*)(ws + 99328);
    float* out = (float*)d_out;

    init_count   <<<1, 64, 0, stream>>>(count);
    triplet_scan <<<NB / 4, 256, 0, stream>>>(a, p, n, count, list, dap, idxmin, row_loss);
    triplet_cols <<<P2_GRID, 256, 0, stream>>>(a, n, count, list, dap, idxmin);
    fixup_reduce <<<1, 256, 0, stream>>>(a, n, count, list, dap, idxmin, row_loss, out);
}